// Round 1
// 806.579 us; speedup vs baseline: 1.0390x; 1.0390x over previous
//
#include <hip/hip_runtime.h>

// ---------------------------------------------------------------------------
// EnterpriseGNN: 3-layer GCN on MI355X.
//   h1 = relu(GCNConv(x, W1, b1));  h2 = relu(GCNConv(h1, W2, b2));
//   out = h2 @ Wout + bout
// GCNConv(x,W,b)[i] = dinv[i] * ( sum_{e:dst=i} w_e * g[src_e] + g[i] ) + b
//   where g = dinv .* (x@W),  dinv = rsqrt(deg+1), deg = sum_{e:dst=i} w_e.
//
// R1: replace scatter-atomic edge aggregation (WRITE_SIZE == E*F*4 proved
// every fp32 atomicAdd writes through to HBM across non-coherent XCD L2s)
// with a CSR built by counting-sort (hist -> scan -> scatter of packed
// (src,w) u64 records), then per-node GATHER for both layers. Aggregation
// HBM writes drop E*F*4 -> N*F*4 (32x); g reads become L2/L3 hits.
// Falls back to the proven atomic path if ws_size is too small.
// ---------------------------------------------------------------------------

#define BLK 256
#define SCAN_CHUNK 1024  // 256 threads * 4 elements
#define MAX_SCAN_BLOCKS 4096

typedef unsigned long long u64;
typedef unsigned int u32;

// ---------------- shared kernels ----------------

__global__ void dinv_kernel(float* __restrict__ deg, int N) {
    int i = blockIdx.x * blockDim.x + threadIdx.x;
    if (i < N) deg[i] = rsqrtf(deg[i] + 1.0f);  // in-place deg -> dinv
}

// g1[i][j] = dinv[i] * sum_k x[i][k] * W1[k][j]   (128 -> 32)
__global__ void gemm1_kernel(const float* __restrict__ x,
                             const float* __restrict__ W1,
                             const float* __restrict__ dinv,
                             float* __restrict__ g1, int N) {
    __shared__ float sW[128 * 32];   // 16 KB
    __shared__ float sx[8][128];     // 4 KB
    for (int i = threadIdx.x; i < 128 * 32; i += BLK) sW[i] = W1[i];
    int node0 = blockIdx.x * 8;
    for (int i = threadIdx.x; i < 8 * 128; i += BLK) {
        int r = i >> 7, c = i & 127;
        int n = node0 + r;
        sx[r][c] = (n < N) ? x[(long long)n * 128 + c] : 0.f;
    }
    __syncthreads();
    int local = threadIdx.x >> 5;     // node within block (0..7)
    int j = threadIdx.x & 31;         // output feature
    int n = node0 + local;
    if (n < N) {
        float acc = 0.f;
#pragma unroll 16
        for (int k = 0; k < 128; k++) acc += sx[local][k] * sW[k * 32 + j];
        g1[n * 32 + j] = acc * dinv[n];
    }
}

// ---------------- CSR path kernels ----------------

// fused: cnt[dst]++ (for CSR) and deg[dst] += w (for normalization)
__global__ void hist_deg_kernel(const int* __restrict__ dst,
                                const float* __restrict__ w,
                                int* __restrict__ cnt,
                                float* __restrict__ deg, int E) {
    int e = blockIdx.x * blockDim.x + threadIdx.x;
    if (e < E) {
        int d = dst[e];
        atomicAdd(&cnt[d], 1);
        atomicAdd(&deg[d], w[e]);
    }
}

__global__ void scan_reduce_kernel(const int* __restrict__ cnt,
                                   int* __restrict__ bsum, int N) {
    __shared__ int sdata[BLK];
    int t = threadIdx.x;
    int base = blockIdx.x * SCAN_CHUNK + t * 4;
    int s = 0;
#pragma unroll
    for (int k = 0; k < 4; k++) {
        int i = base + k;
        if (i < N) s += cnt[i];
    }
    sdata[t] = s;
    __syncthreads();
    for (int d = BLK / 2; d > 0; d >>= 1) {
        if (t < d) sdata[t] += sdata[t + d];
        __syncthreads();
    }
    if (t == 0) bsum[blockIdx.x] = sdata[0];
}

// single block: exclusive scan of bsum[NB] (NB <= MAX_SCAN_BLOCKS)
__global__ void scan_bsum_kernel(int* __restrict__ bsum, int NB) {
    __shared__ int sdata[MAX_SCAN_BLOCKS];
    for (int i = threadIdx.x; i < NB; i += blockDim.x) sdata[i] = bsum[i];
    __syncthreads();
    if (threadIdx.x == 0) {
        int run = 0;
        for (int i = 0; i < NB; i++) { int v = sdata[i]; sdata[i] = run; run += v; }
    }
    __syncthreads();
    for (int i = threadIdx.x; i < NB; i += blockDim.x) bsum[i] = sdata[i];
}

// exclusive scan within block + block offset; writes rowstart A and cursor copy.
// A may alias cnt (each element read then written by the same thread only).
__global__ void scan_final_kernel(const int* __restrict__ cnt,
                                  const int* __restrict__ bsum,
                                  int* __restrict__ A,
                                  int* __restrict__ cur, int N) {
    __shared__ int sdata[BLK];
    int t = threadIdx.x;
    int base = blockIdx.x * SCAN_CHUNK + t * 4;
    int v[4];
    int s = 0;
#pragma unroll
    for (int k = 0; k < 4; k++) {
        int i = base + k;
        v[k] = (i < N) ? cnt[i] : 0;
        s += v[k];
    }
    sdata[t] = s;
    __syncthreads();
    // Hillis-Steele inclusive scan over thread totals
    for (int d = 1; d < BLK; d <<= 1) {
        int xv = (t >= d) ? sdata[t - d] : 0;
        __syncthreads();
        sdata[t] += xv;
        __syncthreads();
    }
    int excl = sdata[t] - s + bsum[blockIdx.x];
#pragma unroll
    for (int k = 0; k < 4; k++) {
        int i = base + k;
        if (i < N) { A[i] = excl; cur[i] = excl; }
        excl += v[k];
    }
}

// packed[pos] = (w_bits<<32) | src, pos from per-dst cursor
__global__ void scatter_kernel(const int* __restrict__ src,
                               const int* __restrict__ dst,
                               const float* __restrict__ w,
                               int* __restrict__ cur,
                               u64* __restrict__ packed, int E) {
    int e = blockIdx.x * blockDim.x + threadIdx.x;
    if (e >= E) return;
    int d = dst[e];
    int pos = atomicAdd(&cur[d], 1);
    u64 p = ((u64)__float_as_uint(w[e]) << 32) | (u32)src[e];
    packed[pos] = p;
}

// per-node gather aggregation + fused GCN epilogue:
//   h[n][f] = relu( dinv[n] * (sum_e w_e * g[src_e][f] + g[n][f]) + bias[f] )
template <int F>
__global__ void gather_kernel(const u64* __restrict__ packed,
                              const int* __restrict__ A,
                              const int* __restrict__ Bend,
                              const float* __restrict__ g,
                              const float* __restrict__ dinv,
                              const float* __restrict__ bias,
                              float* __restrict__ h, int N) {
    const int NPB = BLK / F;
    int f = threadIdx.x & (F - 1);
    int local = threadIdx.x / F;
    int n = blockIdx.x * NPB + local;
    if (n >= N) return;
    int s = A[n], e = Bend[n];
    float acc = g[(size_t)n * F + f];  // self loop, weight 1
    int i = s;
    for (; i + 4 <= e; i += 4) {       // 4-deep MLP on the L2/L3 gathers
        u64 p0 = packed[i], p1 = packed[i + 1];
        u64 p2 = packed[i + 2], p3 = packed[i + 3];
        float ga = g[(size_t)(u32)p0 * F + f];
        float gb = g[(size_t)(u32)p1 * F + f];
        float gc = g[(size_t)(u32)p2 * F + f];
        float gd = g[(size_t)(u32)p3 * F + f];
        acc += __uint_as_float((u32)(p0 >> 32)) * ga;
        acc += __uint_as_float((u32)(p1 >> 32)) * gb;
        acc += __uint_as_float((u32)(p2 >> 32)) * gc;
        acc += __uint_as_float((u32)(p3 >> 32)) * gd;
    }
    for (; i < e; ++i) {
        u64 p = packed[i];
        acc += __uint_as_float((u32)(p >> 32)) * g[(size_t)(u32)p * F + f];
    }
    h[(size_t)n * F + f] = fmaxf(dinv[n] * acc + bias[f], 0.f);
}

// g2[i][j] = dinv[i] * sum_k h1[i][k]*W2[k][j]   (h1 already relu+bias)
__global__ void gemm2_kernel(const float* __restrict__ h1,
                             const float* __restrict__ dinv,
                             const float* __restrict__ W2,
                             float* __restrict__ g2, int N) {
    __shared__ float sW[32 * 16];
    __shared__ float sin_[16][32];
    for (int i = threadIdx.x; i < 32 * 16; i += BLK) sW[i] = W2[i];
    int node0 = blockIdx.x * 16;
    for (int i = threadIdx.x; i < 16 * 32; i += BLK) {
        int r = i >> 5, c = i & 31;
        int n = node0 + r;
        sin_[r][c] = (n < N) ? h1[n * 32 + c] : 0.f;
    }
    __syncthreads();
    int local = threadIdx.x >> 4;
    int j = threadIdx.x & 15;
    int n = node0 + local;
    if (n < N) {
        float acc = 0.f;
#pragma unroll
        for (int k = 0; k < 32; k++) acc += sin_[local][k] * sW[k * 16 + j];
        g2[n * 16 + j] = acc * dinv[n];
    }
}

// out[i] = h2[i] @ Wout + bout   (h2 already relu'd)
__global__ void final_kernel2(const float* __restrict__ h2,
                              const float* __restrict__ Wout,
                              const float* __restrict__ bout,
                              float* __restrict__ out, int N) {
    int n = blockIdx.x * blockDim.x + threadIdx.x;
    if (n >= N) return;
    float o0 = bout[0], o1 = bout[1], o2 = bout[2];
#pragma unroll
    for (int k = 0; k < 16; k++) {
        float v = h2[n * 16 + k];
        o0 += v * Wout[k * 3 + 0];
        o1 += v * Wout[k * 3 + 1];
        o2 += v * Wout[k * 3 + 2];
    }
    out[n * 3 + 0] = o0;
    out[n * 3 + 1] = o1;
    out[n * 3 + 2] = o2;
}

// ---------------- fallback (previous session's atomic path) ----------------

__global__ void deg_kernel(const int* __restrict__ dst,
                           const float* __restrict__ w,
                           float* __restrict__ deg, int E) {
    int e = blockIdx.x * blockDim.x + threadIdx.x;
    if (e < E) atomicAdd(&deg[dst[e]], w[e]);
}

template <int F>
__global__ void edge_agg_kernel(const int* __restrict__ src,
                                const int* __restrict__ dst,
                                const float* __restrict__ w,
                                const float* __restrict__ g,
                                float* __restrict__ agg, int E) {
    unsigned idx = blockIdx.x * blockDim.x + threadIdx.x;
    unsigned total = (unsigned)E * F;
    if (idx >= total) return;
    unsigned e = idx / F;
    unsigned f = idx & (F - 1);
    int s = __ldg(&src[e]);
    int d = __ldg(&dst[e]);
    float we = __ldg(&w[e]);
    atomicAdd(&agg[(unsigned)d * F + f], we * g[(unsigned)s * F + f]);
}

__global__ void layer2_kernel(const float* __restrict__ agg1,
                              const float* __restrict__ g1,
                              const float* __restrict__ dinv,
                              const float* __restrict__ b1,
                              const float* __restrict__ W2,
                              float* __restrict__ g2, int N) {
    __shared__ float sW[32 * 16];
    __shared__ float sin_[16][32];
    for (int i = threadIdx.x; i < 32 * 16; i += BLK) sW[i] = W2[i];
    int node0 = blockIdx.x * 16;
    for (int i = threadIdx.x; i < 16 * 32; i += BLK) {
        int r = i >> 5, c = i & 31;
        int n = node0 + r;
        float v = 0.f;
        if (n < N) {
            float di = dinv[n];
            v = fmaxf(di * (agg1[n * 32 + c] + g1[n * 32 + c]) + b1[c], 0.f);
        }
        sin_[r][c] = v;
    }
    __syncthreads();
    int local = threadIdx.x >> 4;
    int j = threadIdx.x & 15;
    int n = node0 + local;
    if (n < N) {
        float acc = 0.f;
#pragma unroll
        for (int k = 0; k < 32; k++) acc += sin_[local][k] * sW[k * 16 + j];
        g2[n * 16 + j] = acc * dinv[n];
    }
}

__global__ void final_kernel(const float* __restrict__ agg2,
                             const float* __restrict__ g2,
                             const float* __restrict__ dinv,
                             const float* __restrict__ b2,
                             const float* __restrict__ Wout,
                             const float* __restrict__ bout,
                             float* __restrict__ out, int N) {
    int n = blockIdx.x * blockDim.x + threadIdx.x;
    if (n >= N) return;
    float di = dinv[n];
    float o0 = bout[0], o1 = bout[1], o2 = bout[2];
#pragma unroll
    for (int k = 0; k < 16; k++) {
        float v = fmaxf(di * (agg2[n * 16 + k] + g2[n * 16 + k]) + b2[k], 0.f);
        o0 += v * Wout[k * 3 + 0];
        o1 += v * Wout[k * 3 + 1];
        o2 += v * Wout[k * 3 + 2];
    }
    out[n * 3 + 0] = o0;
    out[n * 3 + 1] = o1;
    out[n * 3 + 2] = o2;
}

// ---------------------------------------------------------------------------

extern "C" void kernel_launch(void* const* d_in, const int* in_sizes, int n_in,
                              void* d_out, int out_size, void* d_ws, size_t ws_size,
                              hipStream_t stream) {
    const float* x    = (const float*)d_in[0];
    const int* ei     = (const int*)d_in[1];   // [2, E]: row0 = src, row1 = dst
    const float* ew   = (const float*)d_in[2];
    const float* W1   = (const float*)d_in[3];
    const float* b1   = (const float*)d_in[4];
    const float* W2   = (const float*)d_in[5];
    const float* b2   = (const float*)d_in[6];
    const float* Wout = (const float*)d_in[7];
    const float* bout = (const float*)d_in[8];
    float* out = (float*)d_out;

    const int N = in_sizes[0] / 128;
    const int E = in_sizes[2];
    const int* src = ei;
    const int* dst = ei + E;

    const int NB = (N + SCAN_CHUNK - 1) / SCAN_CHUNK;
    // CSR-path workspace (floats): packed 2E | deg N | cntA N | cur N |
    //                              bsum 4096 | g1 32N | h1 32N | g2 16N | h2 16N
    const size_t needCSR =
        (2 * (size_t)E + 99 * (size_t)N + MAX_SCAN_BLOCKS) * sizeof(float);

    if (ws_size >= needCSR && NB <= MAX_SCAN_BLOCKS) {
        float* ws    = (float*)d_ws;
        u64* packed  = (u64*)ws;                         // 2E floats (8B aligned)
        float* deg   = ws + 2 * (size_t)E;               // N (dinv after dinv_kernel)
        int* cntA    = (int*)(deg + N);                  // N (cnt, then rowstart in place)
        int* cur     = cntA + N;                         // N (cursor; end ptrs after scatter)
        int* bsum    = cur + N;                          // 4096
        float* g1    = (float*)(bsum + MAX_SCAN_BLOCKS); // 32N
        float* h1    = g1 + 32 * (size_t)N;              // 32N
        float* g2    = h1 + 32 * (size_t)N;              // 16N
        float* h2    = g2 + 16 * (size_t)N;              // 16N

        // zero only deg + cnt (0.8 MB) — everything else fully overwritten
        hipMemsetAsync(deg, 0, 2 * (size_t)N * sizeof(float), stream);

        hist_deg_kernel<<<(E + BLK - 1) / BLK, BLK, 0, stream>>>(dst, ew, cntA, deg, E);
        dinv_kernel<<<(N + BLK - 1) / BLK, BLK, 0, stream>>>(deg, N);

        gemm1_kernel<<<(N + 7) / 8, BLK, 0, stream>>>(x, W1, deg, g1, N);

        scan_reduce_kernel<<<NB, BLK, 0, stream>>>(cntA, bsum, N);
        scan_bsum_kernel<<<1, BLK, 0, stream>>>(bsum, NB);
        scan_final_kernel<<<NB, BLK, 0, stream>>>(cntA, bsum, cntA, cur, N);

        scatter_kernel<<<(E + BLK - 1) / BLK, BLK, 0, stream>>>(src, dst, ew, cur,
                                                                packed, E);
        // after scatter: cntA[n] = rowstart, cur[n] = rowend

        gather_kernel<32><<<(N + 7) / 8, BLK, 0, stream>>>(packed, cntA, cur, g1,
                                                           deg, b1, h1, N);
        gemm2_kernel<<<(N + 15) / 16, BLK, 0, stream>>>(h1, deg, W2, g2, N);
        gather_kernel<16><<<(N + 15) / 16, BLK, 0, stream>>>(packed, cntA, cur, g2,
                                                             deg, b2, h2, N);
        final_kernel2<<<(N + BLK - 1) / BLK, BLK, 0, stream>>>(h2, Wout, bout, out, N);
    } else {
        // ---------- fallback: proven atomic path (838 µs) ----------
        float* ws   = (float*)d_ws;
        float* deg  = ws;
        float* agg1 = ws + (size_t)N;
        float* agg2 = ws + (size_t)33 * N;
        float* g1   = ws + (size_t)49 * N;
        float* g2   = ws + (size_t)81 * N;

        hipMemsetAsync(ws, 0, (size_t)49 * N * sizeof(float), stream);

        deg_kernel<<<(E + BLK - 1) / BLK, BLK, 0, stream>>>(dst, ew, deg, E);
        dinv_kernel<<<(N + BLK - 1) / BLK, BLK, 0, stream>>>(deg, N);
        gemm1_kernel<<<(N + 7) / 8, BLK, 0, stream>>>(x, W1, deg, g1, N);
        {
            unsigned total = (unsigned)E * 32u;
            edge_agg_kernel<32><<<(total + BLK - 1) / BLK, BLK, 0, stream>>>(
                src, dst, ew, g1, agg1, E);
        }
        layer2_kernel<<<(N + 15) / 16, BLK, 0, stream>>>(agg1, g1, deg, b1, W2, g2, N);
        {
            unsigned total = (unsigned)E * 16u;
            edge_agg_kernel<16><<<(total + BLK - 1) / BLK, BLK, 0, stream>>>(
                src, dst, ew, g2, agg2, E);
        }
        final_kernel<<<(N + BLK - 1) / BLK, BLK, 0, stream>>>(
            agg2, g2, deg, b2, Wout, bout, out, N);
    }
}

// Round 2
// 671.179 us; speedup vs baseline: 1.2486x; 1.2017x over previous
//
#include <hip/hip_runtime.h>

// ---------------------------------------------------------------------------
// EnterpriseGNN: 3-layer GCN on MI355X.
//   h1 = relu(GCNConv(x, W1, b1));  h2 = relu(GCNConv(h1, W2, b2));
//   out = h2 @ Wout + bout
// GCNConv(x,W,b)[i] = dinv[i] * ( sum_{e:dst=i} w_e * g[src_e] + g[i] ) + b
//   where g = dinv .* (x@W),  dinv = rsqrt(deg+1), deg = sum_{e:dst=i} w_e.
//
// R1: CSR (hist->scan->scatter) + per-node gather replaced scatter atomics.
// R2: hist's TWO scattered atomics per edge (cnt int + deg float, separate
// cache lines) fused into ONE u64 atomic: high word = count, low word =
// fixed-point (2^24) weight sum. Max degree ~70 -> low word < 2^31, no
// carry; deg error ~1e-6, invisible at 1e-3 tolerance. WRITE_SIZE for hist
// should halve (one 8B location/edge instead of two 4B on distinct lines).
// ---------------------------------------------------------------------------

#define BLK 256
#define SCAN_CHUNK 1024  // 256 threads * 4 elements
#define MAX_SCAN_BLOCKS 4096
#define FIXED_SCALE 16777216.0f  // 2^24

typedef unsigned long long u64;
typedef unsigned int u32;

// ---------------- CSR path kernels ----------------

// one u64 atomic per edge: cnt64[d] += (1<<32) | round(w * 2^24)
__global__ void hist_kernel(const int* __restrict__ dst,
                            const float* __restrict__ w,
                            u64* __restrict__ cnt64, int E) {
    int e = blockIdx.x * blockDim.x + threadIdx.x;
    if (e < E) {
        int d = dst[e];
        u64 inc = (1ULL << 32) | (u64)(u32)(w[e] * FIXED_SCALE + 0.5f);
        atomicAdd(&cnt64[d], inc);
    }
}

// dinv[i] = rsqrt(deg + 1), deg = low32(cnt64[i]) / 2^24
__global__ void dinv_kernel(const u64* __restrict__ cnt64,
                            float* __restrict__ dinv, int N) {
    int i = blockIdx.x * blockDim.x + threadIdx.x;
    if (i < N) {
        float deg = (float)(u32)cnt64[i] * (1.0f / FIXED_SCALE);
        dinv[i] = rsqrtf(deg + 1.0f);
    }
}

__global__ void scan_reduce_kernel(const u64* __restrict__ cnt64,
                                   int* __restrict__ bsum, int N) {
    __shared__ int sdata[BLK];
    int t = threadIdx.x;
    int base = blockIdx.x * SCAN_CHUNK + t * 4;
    int s = 0;
#pragma unroll
    for (int k = 0; k < 4; k++) {
        int i = base + k;
        if (i < N) s += (int)(cnt64[i] >> 32);
    }
    sdata[t] = s;
    __syncthreads();
    for (int d = BLK / 2; d > 0; d >>= 1) {
        if (t < d) sdata[t] += sdata[t + d];
        __syncthreads();
    }
    if (t == 0) bsum[blockIdx.x] = sdata[0];
}

// single block: exclusive scan of bsum[NB] (NB <= MAX_SCAN_BLOCKS)
__global__ void scan_bsum_kernel(int* __restrict__ bsum, int NB) {
    __shared__ int sdata[MAX_SCAN_BLOCKS];
    for (int i = threadIdx.x; i < NB; i += blockDim.x) sdata[i] = bsum[i];
    __syncthreads();
    if (threadIdx.x == 0) {
        int run = 0;
        for (int i = 0; i < NB; i++) { int v = sdata[i]; sdata[i] = run; run += v; }
    }
    __syncthreads();
    for (int i = threadIdx.x; i < NB; i += blockDim.x) bsum[i] = sdata[i];
}

// exclusive scan within block + block offset; writes rowstart A and cursor.
__global__ void scan_final_kernel(const u64* __restrict__ cnt64,
                                  const int* __restrict__ bsum,
                                  int* __restrict__ A,
                                  int* __restrict__ cur, int N) {
    __shared__ int sdata[BLK];
    int t = threadIdx.x;
    int base = blockIdx.x * SCAN_CHUNK + t * 4;
    int v[4];
    int s = 0;
#pragma unroll
    for (int k = 0; k < 4; k++) {
        int i = base + k;
        v[k] = (i < N) ? (int)(cnt64[i] >> 32) : 0;
        s += v[k];
    }
    sdata[t] = s;
    __syncthreads();
    // Hillis-Steele inclusive scan over thread totals
    for (int d = 1; d < BLK; d <<= 1) {
        int xv = (t >= d) ? sdata[t - d] : 0;
        __syncthreads();
        sdata[t] += xv;
        __syncthreads();
    }
    int excl = sdata[t] - s + bsum[blockIdx.x];
#pragma unroll
    for (int k = 0; k < 4; k++) {
        int i = base + k;
        if (i < N) { A[i] = excl; cur[i] = excl; }
        excl += v[k];
    }
}

// packed[pos] = (w_bits<<32) | src, pos from per-dst cursor
__global__ void scatter_kernel(const int* __restrict__ src,
                               const int* __restrict__ dst,
                               const float* __restrict__ w,
                               int* __restrict__ cur,
                               u64* __restrict__ packed, int E) {
    int e = blockIdx.x * blockDim.x + threadIdx.x;
    if (e >= E) return;
    int d = dst[e];
    int pos = atomicAdd(&cur[d], 1);
    u64 p = ((u64)__float_as_uint(w[e]) << 32) | (u32)src[e];
    packed[pos] = p;
}

// per-node gather aggregation + fused GCN epilogue:
//   h[n][f] = relu( dinv[n] * (sum_e w_e * g[src_e][f] + g[n][f]) + bias[f] )
template <int F>
__global__ void gather_kernel(const u64* __restrict__ packed,
                              const int* __restrict__ A,
                              const int* __restrict__ Bend,
                              const float* __restrict__ g,
                              const float* __restrict__ dinv,
                              const float* __restrict__ bias,
                              float* __restrict__ h, int N) {
    const int NPB = BLK / F;
    int f = threadIdx.x & (F - 1);
    int local = threadIdx.x / F;
    int n = blockIdx.x * NPB + local;
    if (n >= N) return;
    int s = A[n], e = Bend[n];
    float acc = g[(size_t)n * F + f];  // self loop, weight 1
    int i = s;
    for (; i + 4 <= e; i += 4) {       // 4-deep MLP on the L2/L3 gathers
        u64 p0 = packed[i], p1 = packed[i + 1];
        u64 p2 = packed[i + 2], p3 = packed[i + 3];
        float ga = g[(size_t)(u32)p0 * F + f];
        float gb = g[(size_t)(u32)p1 * F + f];
        float gc = g[(size_t)(u32)p2 * F + f];
        float gd = g[(size_t)(u32)p3 * F + f];
        acc += __uint_as_float((u32)(p0 >> 32)) * ga;
        acc += __uint_as_float((u32)(p1 >> 32)) * gb;
        acc += __uint_as_float((u32)(p2 >> 32)) * gc;
        acc += __uint_as_float((u32)(p3 >> 32)) * gd;
    }
    for (; i < e; ++i) {
        u64 p = packed[i];
        acc += __uint_as_float((u32)(p >> 32)) * g[(size_t)(u32)p * F + f];
    }
    h[(size_t)n * F + f] = fmaxf(dinv[n] * acc + bias[f], 0.f);
}

// g1[i][j] = dinv[i] * sum_k x[i][k] * W1[k][j]   (128 -> 32)
__global__ void gemm1_kernel(const float* __restrict__ x,
                             const float* __restrict__ W1,
                             const float* __restrict__ dinv,
                             float* __restrict__ g1, int N) {
    __shared__ float sW[128 * 32];   // 16 KB
    __shared__ float sx[8][128];     // 4 KB
    const float4* W4 = (const float4*)W1;
    float4* sW4 = (float4*)sW;
    for (int i = threadIdx.x; i < 1024; i += BLK) sW4[i] = W4[i];
    int node0 = blockIdx.x * 8;
    {
        int r = threadIdx.x >> 5, c4 = threadIdx.x & 31;  // 8 rows x 32 float4
        int n = node0 + r;
        float4 v = make_float4(0.f, 0.f, 0.f, 0.f);
        if (n < N) v = *(const float4*)&x[(size_t)n * 128 + c4 * 4];
        *(float4*)&sx[r][c4 * 4] = v;
    }
    __syncthreads();
    int local = threadIdx.x >> 5;     // node within block (0..7)
    int j = threadIdx.x & 31;         // output feature
    int n = node0 + local;
    if (n < N) {
        float acc = 0.f;
#pragma unroll 16
        for (int k = 0; k < 128; k++) acc += sx[local][k] * sW[k * 32 + j];
        g1[n * 32 + j] = acc * dinv[n];
    }
}

// g2[i][j] = dinv[i] * sum_k h1[i][k]*W2[k][j]   (h1 already relu+bias)
__global__ void gemm2_kernel(const float* __restrict__ h1,
                             const float* __restrict__ dinv,
                             const float* __restrict__ W2,
                             float* __restrict__ g2, int N) {
    __shared__ float sW[32 * 16];
    __shared__ float sin_[16][32];
    for (int i = threadIdx.x; i < 32 * 16; i += BLK) sW[i] = W2[i];
    int node0 = blockIdx.x * 16;
    for (int i = threadIdx.x; i < 16 * 32; i += BLK) {
        int r = i >> 5, c = i & 31;
        int n = node0 + r;
        sin_[r][c] = (n < N) ? h1[n * 32 + c] : 0.f;
    }
    __syncthreads();
    int local = threadIdx.x >> 4;
    int j = threadIdx.x & 15;
    int n = node0 + local;
    if (n < N) {
        float acc = 0.f;
#pragma unroll
        for (int k = 0; k < 32; k++) acc += sin_[local][k] * sW[k * 16 + j];
        g2[n * 16 + j] = acc * dinv[n];
    }
}

// out[i] = h2[i] @ Wout + bout   (h2 already relu'd)
__global__ void final_kernel2(const float* __restrict__ h2,
                              const float* __restrict__ Wout,
                              const float* __restrict__ bout,
                              float* __restrict__ out, int N) {
    int n = blockIdx.x * blockDim.x + threadIdx.x;
    if (n >= N) return;
    float o0 = bout[0], o1 = bout[1], o2 = bout[2];
#pragma unroll
    for (int k = 0; k < 16; k++) {
        float v = h2[n * 16 + k];
        o0 += v * Wout[k * 3 + 0];
        o1 += v * Wout[k * 3 + 1];
        o2 += v * Wout[k * 3 + 2];
    }
    out[n * 3 + 0] = o0;
    out[n * 3 + 1] = o1;
    out[n * 3 + 2] = o2;
}

// ---------------- fallback (exact atomic path) ----------------

__global__ void deg_kernel(const int* __restrict__ dst,
                           const float* __restrict__ w,
                           float* __restrict__ deg, int E) {
    int e = blockIdx.x * blockDim.x + threadIdx.x;
    if (e < E) atomicAdd(&deg[dst[e]], w[e]);
}

__global__ void dinvf_kernel(float* __restrict__ deg, int N) {
    int i = blockIdx.x * blockDim.x + threadIdx.x;
    if (i < N) deg[i] = rsqrtf(deg[i] + 1.0f);
}

template <int F>
__global__ void edge_agg_kernel(const int* __restrict__ src,
                                const int* __restrict__ dst,
                                const float* __restrict__ w,
                                const float* __restrict__ g,
                                float* __restrict__ agg, int E) {
    unsigned idx = blockIdx.x * blockDim.x + threadIdx.x;
    unsigned total = (unsigned)E * F;
    if (idx >= total) return;
    unsigned e = idx / F;
    unsigned f = idx & (F - 1);
    int s = __ldg(&src[e]);
    int d = __ldg(&dst[e]);
    float we = __ldg(&w[e]);
    atomicAdd(&agg[(unsigned)d * F + f], we * g[(unsigned)s * F + f]);
}

__global__ void layer2_kernel(const float* __restrict__ agg1,
                              const float* __restrict__ g1,
                              const float* __restrict__ dinv,
                              const float* __restrict__ b1,
                              const float* __restrict__ W2,
                              float* __restrict__ g2, int N) {
    __shared__ float sW[32 * 16];
    __shared__ float sin_[16][32];
    for (int i = threadIdx.x; i < 32 * 16; i += BLK) sW[i] = W2[i];
    int node0 = blockIdx.x * 16;
    for (int i = threadIdx.x; i < 16 * 32; i += BLK) {
        int r = i >> 5, c = i & 31;
        int n = node0 + r;
        float v = 0.f;
        if (n < N) {
            float di = dinv[n];
            v = fmaxf(di * (agg1[n * 32 + c] + g1[n * 32 + c]) + b1[c], 0.f);
        }
        sin_[r][c] = v;
    }
    __syncthreads();
    int local = threadIdx.x >> 4;
    int j = threadIdx.x & 15;
    int n = node0 + local;
    if (n < N) {
        float acc = 0.f;
#pragma unroll
        for (int k = 0; k < 32; k++) acc += sin_[local][k] * sW[k * 16 + j];
        g2[n * 16 + j] = acc * dinv[n];
    }
}

__global__ void final_kernel(const float* __restrict__ agg2,
                             const float* __restrict__ g2,
                             const float* __restrict__ dinv,
                             const float* __restrict__ b2,
                             const float* __restrict__ Wout,
                             const float* __restrict__ bout,
                             float* __restrict__ out, int N) {
    int n = blockIdx.x * blockDim.x + threadIdx.x;
    if (n >= N) return;
    float di = dinv[n];
    float o0 = bout[0], o1 = bout[1], o2 = bout[2];
#pragma unroll
    for (int k = 0; k < 16; k++) {
        float v = fmaxf(di * (agg2[n * 16 + k] + g2[n * 16 + k]) + b2[k], 0.f);
        o0 += v * Wout[k * 3 + 0];
        o1 += v * Wout[k * 3 + 1];
        o2 += v * Wout[k * 3 + 2];
    }
    out[n * 3 + 0] = o0;
    out[n * 3 + 1] = o1;
    out[n * 3 + 2] = o2;
}

// ---------------------------------------------------------------------------

extern "C" void kernel_launch(void* const* d_in, const int* in_sizes, int n_in,
                              void* d_out, int out_size, void* d_ws, size_t ws_size,
                              hipStream_t stream) {
    const float* x    = (const float*)d_in[0];
    const int* ei     = (const int*)d_in[1];   // [2, E]: row0 = src, row1 = dst
    const float* ew   = (const float*)d_in[2];
    const float* W1   = (const float*)d_in[3];
    const float* b1   = (const float*)d_in[4];
    const float* W2   = (const float*)d_in[5];
    const float* b2   = (const float*)d_in[6];
    const float* Wout = (const float*)d_in[7];
    const float* bout = (const float*)d_in[8];
    float* out = (float*)d_out;

    const int N = in_sizes[0] / 128;
    const int E = in_sizes[2];
    const int* src = ei;
    const int* dst = ei + E;

    const int NB = (N + SCAN_CHUNK - 1) / SCAN_CHUNK;
    // CSR-path workspace (floats): packed 2E | cnt64 2N | rowA N | cur N |
    //                              bsum 4096 | dinv N | g1 32N | h1 32N |
    //                              g2 16N | h2 16N        = 2E + 101N + 4096
    const size_t needCSR =
        (2 * (size_t)E + 101 * (size_t)N + MAX_SCAN_BLOCKS) * sizeof(float);

    if (ws_size >= needCSR && NB <= MAX_SCAN_BLOCKS) {
        float* ws    = (float*)d_ws;
        u64* packed  = (u64*)ws;                          // 2E floats (8B aligned)
        u64* cnt64   = (u64*)(ws + 2 * (size_t)E);        // 2N floats (8B aligned)
        int* rowA    = (int*)(ws + 4 * (size_t)E == 0 ? 0 : (ws + 2 * (size_t)E + 2 * (size_t)N));
        int* cur     = rowA + N;                          // N
        int* bsum    = cur + N;                           // 4096
        float* dinv  = (float*)(bsum + MAX_SCAN_BLOCKS);  // N
        float* g1    = dinv + (size_t)N;                  // 32N
        float* h1    = g1 + 32 * (size_t)N;               // 32N
        float* g2    = h1 + 32 * (size_t)N;               // 16N
        float* h2    = g2 + 16 * (size_t)N;               // 16N

        // zero only cnt64 (0.8 MB) — everything else fully overwritten
        hipMemsetAsync(cnt64, 0, (size_t)N * sizeof(u64), stream);

        hist_kernel<<<(E + BLK - 1) / BLK, BLK, 0, stream>>>(dst, ew, cnt64, E);
        dinv_kernel<<<(N + BLK - 1) / BLK, BLK, 0, stream>>>(cnt64, dinv, N);

        gemm1_kernel<<<(N + 7) / 8, BLK, 0, stream>>>(x, W1, dinv, g1, N);

        scan_reduce_kernel<<<NB, BLK, 0, stream>>>(cnt64, bsum, N);
        scan_bsum_kernel<<<1, BLK, 0, stream>>>(bsum, NB);
        scan_final_kernel<<<NB, BLK, 0, stream>>>(cnt64, bsum, rowA, cur, N);

        scatter_kernel<<<(E + BLK - 1) / BLK, BLK, 0, stream>>>(src, dst, ew, cur,
                                                                packed, E);
        // after scatter: rowA[n] = rowstart, cur[n] = rowend

        gather_kernel<32><<<(N + 7) / 8, BLK, 0, stream>>>(packed, rowA, cur, g1,
                                                           dinv, b1, h1, N);
        gemm2_kernel<<<(N + 15) / 16, BLK, 0, stream>>>(h1, dinv, W2, g2, N);
        gather_kernel<16><<<(N + 15) / 16, BLK, 0, stream>>>(packed, rowA, cur, g2,
                                                             dinv, b2, h2, N);
        final_kernel2<<<(N + BLK - 1) / BLK, BLK, 0, stream>>>(h2, Wout, bout, out, N);
    } else {
        // ---------- fallback: proven atomic path ----------
        float* ws   = (float*)d_ws;
        float* deg  = ws;
        float* agg1 = ws + (size_t)N;
        float* agg2 = ws + (size_t)33 * N;
        float* g1   = ws + (size_t)49 * N;
        float* g2   = ws + (size_t)81 * N;

        hipMemsetAsync(ws, 0, (size_t)49 * N * sizeof(float), stream);

        deg_kernel<<<(E + BLK - 1) / BLK, BLK, 0, stream>>>(dst, ew, deg, E);
        dinvf_kernel<<<(N + BLK - 1) / BLK, BLK, 0, stream>>>(deg, N);
        gemm1_kernel<<<(N + 7) / 8, BLK, 0, stream>>>(x, W1, deg, g1, N);
        {
            unsigned total = (unsigned)E * 32u;
            edge_agg_kernel<32><<<(total + BLK - 1) / BLK, BLK, 0, stream>>>(
                src, dst, ew, g1, agg1, E);
        }
        layer2_kernel<<<(N + 15) / 16, BLK, 0, stream>>>(agg1, g1, deg, b1, W2, g2, N);
        {
            unsigned total = (unsigned)E * 16u;
            edge_agg_kernel<16><<<(total + BLK - 1) / BLK, BLK, 0, stream>>>(
                src, dst, ew, g2, agg2, E);
        }
        final_kernel<<<(N + BLK - 1) / BLK, BLK, 0, stream>>>(
            agg2, g2, deg, b2, Wout, bout, out, N);
    }
}